// Round 7
// baseline (2660.456 us; speedup 1.0000x reference)
//
#include <hip/hip_runtime.h>

// B=256, D=128, T=512, E=128, H=512, WH=512, WIN=64
typedef __attribute__((ext_vector_type(8))) short s8v;
typedef __attribute__((ext_vector_type(4))) float f4v;
typedef __attribute__((ext_vector_type(4))) unsigned int u4v;

#define MFMA16(a, b, c) __builtin_amdgcn_mfma_f32_16x16x32_bf16((a), (b), (c), 0, 0, 0)

__device__ __forceinline__ unsigned short f2bf(float f) {
  unsigned u = __float_as_uint(f);
  return (unsigned short)((u + 0x7fffu + ((u >> 16) & 1u)) >> 16);
}

// ---------- fp32 -> bf16 conversion (vectorized by 4) ----------
__global__ void cvt4_kernel(const float* __restrict__ in, unsigned short* __restrict__ out, int n4) {
  int i = blockIdx.x * blockDim.x + threadIdx.x;
  if (i >= n4) return;
  float4 v = ((const float4*)in)[i];
  ushort4 o;
  o.x = f2bf(v.x); o.y = f2bf(v.y); o.z = f2bf(v.z); o.w = f2bf(v.w);
  ((ushort4*)out)[i] = o;
}

// ---------- slow_input = [context | e] as bf16 (256 x 640) ----------
__global__ void build_slow_kernel(const float* __restrict__ context, const float* __restrict__ e,
                                  unsigned short* __restrict__ out) {
  int i = blockIdx.x * blockDim.x + threadIdx.x;
  if (i >= 256 * 640) return;
  int b = i / 640, c = i - b * 640;
  float v = (c < 512) ? context[b * 512 + c] : e[b * 128 + (c - 512)];
  out[i] = f2bf(v);
}

// ---------- generic GEMM: C[M][N] = act(A[M][K] @ B[N][K]^T + bias), bf16 in fp32 out ----------
template <int RELU>
__global__ __launch_bounds__(256) void gemm_bt(const unsigned short* __restrict__ A,
                                               const unsigned short* __restrict__ B,
                                               const float* __restrict__ bias, float* __restrict__ C,
                                               int M, int N, int K) {
  __shared__ unsigned short As[64][48];
  __shared__ unsigned short Bs[64][48];
  int tid = threadIdx.x;
  int lane = tid & 63, w = tid >> 6;
  int m = lane & 15, q = lane >> 4;
  int row0 = blockIdx.x * 64, col0 = blockIdx.y * 64;
  int sr = tid >> 2, sk = (tid & 3) * 8;
  const unsigned short* Ap = A + (size_t)(row0 + sr) * K + sk;
  const unsigned short* Bp = B + (size_t)(col0 + sr) * K + sk;
  f4v acc[4];
#pragma unroll
  for (int nt = 0; nt < 4; nt++) acc[nt] = (f4v){0.f, 0.f, 0.f, 0.f};

  for (int k0 = 0; k0 < K; k0 += 32) {
    *(uint4*)&As[sr][sk] = *(const uint4*)(Ap + k0);
    *(uint4*)&Bs[sr][sk] = *(const uint4*)(Bp + k0);
    __syncthreads();
    s8v a = *(const s8v*)&As[w * 16 + m][q * 8];
#pragma unroll
    for (int nt = 0; nt < 4; nt++) {
      s8v bb = *(const s8v*)&Bs[nt * 16 + m][q * 8];
      acc[nt] = MFMA16(a, bb, acc[nt]);
    }
    __syncthreads();
  }
#pragma unroll
  for (int nt = 0; nt < 4; nt++) {
    int c = col0 + nt * 16 + m;
    float bv = bias[c];
#pragma unroll
    for (int i = 0; i < 4; i++) {
      int r = row0 + w * 16 + q * 4 + i;
      float v = acc[nt][i] + bv;
      if (RELU) v = v > 0.f ? v : 0.f;
      C[(size_t)r * N + c] = v;
    }
  }
}

// ---------- phase C: distributed GRU scan, v6b (request-shaped exchange) ----------
// Geometry (v5, verified): 256 WGs x 64 thr = 16 bg x 16 cg, 96 KB LDS W-slice.
// v6 changes ONLY the exchange transaction shape (v5 timing showed MALL
// request contention, not bytes: HBM 4%, FETCH up while time down):
//  - h-loads: 16x global_load_dwordx4 sc0 sc1 (16B, non-atomic, MALL-bypass)
//    instead of 32x atomic u64. Hall[t] addresses are write-once -> no tearing;
//    visibility gated by flags.
//  - poll: lanes 0-3 load 16 flags as dwordx4 sc0 sc1 (4 req/iter vs 64).
//    Monotonic u32s -> torn 16B reads harmless. Hedge fence every 64 failed
//    spins -> wrong sc-bit model degrades to correct-but-slow, never silent.
//  - h-stores: K-permutation (physical u64 slot s = cg*8+q*2+ct) makes each
//    lane's pair adjacent -> one dwordx4 sc0 sc1 store (payload built in an
//    ext_vector u4v register, element-wise — union-member asm inputs don't
//    lower to VGPRs, round-6 compile error).
// K-permutation: physical elem p = kc*32+q*8+(ct*4+i) holds logical col
// c = kc*32 + ct*16 + q*4 + i. W_hh LDS staging and fc_scan's Wfc fragments
// load the matching {kc*32+q*4, kc*32+16+q*4} 4-col pairs (bijective), so the
// MFMA contraction is exact.
__global__ __launch_bounds__(64) void gru_scan6(const float* __restrict__ gi,
                                                const unsigned short* __restrict__ Whh,
                                                const float* __restrict__ bhh,
                                                unsigned long long* __restrict__ Hall8,
                                                unsigned int* __restrict__ flags) {
  __shared__ unsigned short wlds[6 * 16 * 64 * 8];  // 96 KB: [gc=g*2+ct][kc][lane][8]
  int tid = threadIdx.x;
  int bid = blockIdx.x;
  int bg = bid >> 4, cg = bid & 15;
  int b0 = bg * 16;
  int n = tid & 15, q = tid >> 4;

  // stage W slice into LDS in PERMUTED A-fragment order (one-time, 96 KB)
#pragma unroll 1
  for (int it = 0; it < 96; ++it) {
    int g = it >> 5, rem = it & 31, ct = rem >> 4, kc = rem & 15;
    int row = g * 512 + cg * 32 + ct * 16 + n;
    const unsigned short* wb = Whh + (size_t)row * 512 + kc * 32;
    unsigned short* dst = &wlds[(((g * 2 + ct) * 16 + kc) * 64 + tid) * 8];
    *(uint2*)dst = *(const uint2*)(wb + q * 4);            // logical cols kc*32+q*4..+3
    *(uint2*)(dst + 4) = *(const uint2*)(wb + 16 + q * 4); // logical cols kc*32+16+q*4..+3
  }

  // time-invariant gate inputs (logical col indexing unchanged)
  float gir[2][4], giz[2][4], gin[2][4], bhn[2][4];
#pragma unroll
  for (int ct = 0; ct < 2; ++ct) {
#pragma unroll
    for (int i = 0; i < 4; ++i) {
      int c = cg * 32 + ct * 16 + q * 4 + i;
      const float* gp = gi + (size_t)(b0 + n) * 1536 + c;
      gir[ct][i] = gp[0] + bhh[c];
      giz[ct][i] = gp[512] + bhh[c + 512];
      gin[ct][i] = gp[1024];
      bhn[ct][i] = bhh[c + 1024];
    }
  }
  float hp[2][4] = {{0.f, 0.f, 0.f, 0.f}, {0.f, 0.f, 0.f, 0.f}};
  __syncthreads();

  unsigned int* myflag = flags + bg * 32 + cg;
  const unsigned int* pollp = flags + bg * 32 + (tid & 3) * 4;  // lanes 0-3: 4 flags each
  size_t rowbase = (size_t)(b0 + n) * 512 * 128;  // 128 u64 per (b,t)

#pragma unroll 1
  for (int t = 0; t < 512; ++t) {
    f4v ar[2], az[2], an[2];
#pragma unroll
    for (int ct = 0; ct < 2; ++ct) {
      ar[ct] = (f4v){gir[ct][0], gir[ct][1], gir[ct][2], gir[ct][3]};
      az[ct] = (f4v){giz[ct][0], giz[ct][1], giz[ct][2], giz[ct][3]};
      an[ct] = (f4v){bhn[ct][0], bhn[ct][1], bhn[ct][2], bhn[ct][3]};
    }
    if (t > 0) {
      unsigned tgt = (unsigned)t;
      for (long sp = 0; sp < 500000L; ++sp) {
        unsigned m0 = tgt, m1 = tgt, m2 = tgt, m3 = tgt;
        if (tid < 4) {
          u4v fv;
          asm volatile("global_load_dwordx4 %0, %1, off sc0 sc1\n\ts_waitcnt vmcnt(0)"
                       : "=v"(fv)
                       : "v"(pollp)
                       : "memory");
          m0 = fv[0]; m1 = fv[1]; m2 = fv[2]; m3 = fv[3];
        }
        bool ok = (m0 >= tgt) && (m1 >= tgt) && (m2 >= tgt) && (m3 >= tgt);
        if (__ballot(ok) == 0xffffffffffffffffULL) break;
        // hedge: if sc0 sc1 doesn't bypass caches, force refetch often enough
        // that we degrade to slow-but-correct (visible failure, not silent)
        if ((sp & 63) == 63) __builtin_amdgcn_fence(__ATOMIC_ACQUIRE, "agent");
      }
      asm volatile("" ::: "memory");
      const char* hb = (const char*)(Hall8 + rowbase + (size_t)(t - 1) * 128) + q * 16;
      s8v bf[16];
#pragma unroll
      for (int kc = 0; kc < 16; ++kc) {
        asm volatile("global_load_dwordx4 %0, %1, off sc0 sc1"
                     : "=v"(bf[kc])
                     : "v"(hb + (size_t)kc * 64)
                     : "memory");
      }
      asm volatile("s_waitcnt vmcnt(0)" ::: "memory");
      __builtin_amdgcn_sched_barrier(0);
#pragma unroll
      for (int kc = 0; kc < 16; ++kc) {
#pragma unroll
        for (int ct = 0; ct < 2; ++ct) {
          s8v a0 = *(const s8v*)&wlds[(((0 + ct) * 16 + kc) * 64 + tid) * 8];
          ar[ct] = MFMA16(a0, bf[kc], ar[ct]);
          s8v a1 = *(const s8v*)&wlds[(((2 + ct) * 16 + kc) * 64 + tid) * 8];
          az[ct] = MFMA16(a1, bf[kc], az[ct]);
          s8v a2 = *(const s8v*)&wlds[(((4 + ct) * 16 + kc) * 64 + tid) * 8];
          an[ct] = MFMA16(a2, bf[kc], an[ct]);
        }
      }
    }
    unsigned long long hu[2];
#pragma unroll
    for (int ct = 0; ct < 2; ++ct) {
      union { unsigned short s[4]; unsigned long long u; } pk;
#pragma unroll
      for (int i = 0; i < 4; ++i) {
        float r = 1.f / (1.f + __expf(-ar[ct][i]));
        float zg = 1.f / (1.f + __expf(-az[ct][i]));
        float x = gin[ct][i] + r * an[ct][i];
        float ex = __expf(2.f * x);
        float nn = 1.f - 2.f / (ex + 1.f);
        float h = (1.f - zg) * nn + zg * hp[ct][i];
        hp[ct][i] = h;
        pk.s[i] = f2bf(h);
      }
      hu[ct] = pk.u;
    }
    {
      // build 128-bit payload in an ext_vector register (element-wise; no union
      // member access — that fails to lower as an asm "v" input, round 6)
      u4v stv;
      stv[0] = (unsigned)hu[0];
      stv[1] = (unsigned)(hu[0] >> 32);
      stv[2] = (unsigned)hu[1];
      stv[3] = (unsigned)(hu[1] >> 32);
      unsigned long long* hstp = Hall8 + rowbase + (size_t)t * 128 + (size_t)(cg * 8 + q * 2);
      asm volatile("global_store_dwordx4 %0, %1, off sc0 sc1" ::"v"(hstp), "v"(stv) : "memory");
    }
    asm volatile("s_waitcnt vmcnt(0)" ::: "memory");
    if (tid == 0) {
      unsigned fv = (unsigned)(t + 1);
      asm volatile("global_store_dword %0, %1, off sc0 sc1" ::"v"(myflag), "v"(fv) : "memory");
    }
  }
}

// ---------- phase D+E fused: inc = Hall @ Wfc^T + bfc; out = zp0 + cumsum_t(inc) ----------
// NOTE: Hall rows are in PERMUTED K order; wf fragments load the matching
// {kc*32+q*4, kc*32+16+q*4} logical-col pairs so the contraction is exact.
__global__ __launch_bounds__(256) void fc_scan(const unsigned short* __restrict__ Hall,
                                               const unsigned short* __restrict__ Wfc,
                                               const float* __restrict__ bfc,
                                               const float* __restrict__ zctx,
                                               float* __restrict__ out) {
  __shared__ unsigned short hs[16][520];
  int tid = threadIdx.x;
  int lane = tid & 63, w = tid >> 6;
  int m = lane & 15, q = lane >> 4;
  int b = blockIdx.x;

  s8v wf[2][16];
  float bf_r[2], carry[2];
#pragma unroll
  for (int j = 0; j < 2; j++) {
    int d = (2 * w + j) * 16 + m;
#pragma unroll
    for (int kc = 0; kc < 16; kc++) {
      const unsigned short* wb = Wfc + (size_t)d * 512 + kc * 32;
      union { uint2 u2[2]; s8v v; } wu;
      wu.u2[0] = *(const uint2*)(wb + q * 4);
      wu.u2[1] = *(const uint2*)(wb + 16 + q * 4);
      wf[j][kc] = wu.v;
    }
    bf_r[j] = bfc[d];
    carry[j] = zctx[((size_t)b * 128 + d) * 64 + 63];
  }

#pragma unroll 1
  for (int chunk = 0; chunk < 32; chunk++) {
    int t0 = chunk * 16;
    {
      int mm = tid >> 4, ci = (tid & 15) * 4;
      const unsigned short* src = Hall + ((size_t)b * 512 + t0 + mm) * 512 + ci * 8;
#pragma unroll
      for (int o = 0; o < 4; o++) {
        uint4 v = *(const uint4*)(src + o * 8);
        *(uint4*)&hs[mm][(ci + o) * 8] = v;
      }
    }
    __syncthreads();
    s8v af[16];
#pragma unroll
    for (int kc = 0; kc < 16; kc++) af[kc] = *(const s8v*)&hs[m][kc * 32 + q * 8];
    f4v acc[2];
    acc[0] = (f4v){0.f, 0.f, 0.f, 0.f};
    acc[1] = (f4v){0.f, 0.f, 0.f, 0.f};
#pragma unroll
    for (int kc = 0; kc < 16; kc++) {
      acc[0] = MFMA16(af[kc], wf[0][kc], acc[0]);
      acc[1] = MFMA16(af[kc], wf[1][kc], acc[1]);
    }
    __syncthreads();

#pragma unroll
    for (int j = 0; j < 2; j++) {
      float s0 = acc[j][0] + bf_r[j];
      float s1 = s0 + acc[j][1] + bf_r[j];
      float s2 = s1 + acc[j][2] + bf_r[j];
      float s3 = s2 + acc[j][3] + bf_r[j];
      float tot = s3;
      float incl = tot;
      float u = __shfl_up(incl, 16, 64);
      if (q >= 1) incl += u;
      u = __shfl_up(incl, 32, 64);
      if (q >= 2) incl += u;
      float excl = incl - tot;
      float add = excl + carry[j];
      int d = (2 * w + j) * 16 + m;
      float4 o4 = make_float4(s0 + add, s1 + add, s2 + add, s3 + add);
      *(float4*)(out + ((size_t)b * 128 + d) * 512 + t0 + q * 4) = o4;
      float chunktot = __shfl(incl, 48 + m, 64);
      carry[j] += chunktot;
    }
  }
}

extern "C" void kernel_launch(void* const* d_in, const int* in_sizes, int n_in,
                              void* d_out, int out_size, void* d_ws, size_t ws_size,
                              hipStream_t stream) {
  const float* z_ctx = (const float*)d_in[0];
  const float* e     = (const float*)d_in[4];
  const float* W_enc = (const float*)d_in[5];
  const float* b_enc = (const float*)d_in[6];
  const float* W_ih  = (const float*)d_in[7];
  const float* W_hh  = (const float*)d_in[8];
  const float* b_ih  = (const float*)d_in[9];
  const float* b_hh  = (const float*)d_in[10];
  const float* W_fc  = (const float*)d_in[11];
  const float* b_fc  = (const float*)d_in[12];
  float* out = (float*)d_out;

  char* ws = (char*)d_ws;
  const size_t OFF_WENC = 0;          // 512*8192*2
  const size_t OFF_ZCTX = 8388608;    // 256*8192*2
  const size_t OFF_WIH  = 12582912;   // 1536*640*2
  const size_t OFF_WHH  = 14548992;   // 1536*512*2
  const size_t OFF_WFC  = 16121856;   // 128*512*2
  const size_t OFF_CTX  = 16252928;   // 256*512*4
  const size_t OFF_SLOW = 16777216;   // 256*640*2
  const size_t OFF_GI   = 17104896;   // 256*1536*4
  const size_t OFF_HALL = 18677760;   // 256*512*512*2
  const size_t OFF_SYNC = OFF_HALL + 134217728ull;  // flags (32KB reserved)
  const size_t NEED = OFF_SYNC + 32768;
  if (ws_size < NEED) return;

  unsigned short* Wenc_bf = (unsigned short*)(ws + OFF_WENC);
  unsigned short* zctx_bf = (unsigned short*)(ws + OFF_ZCTX);
  unsigned short* Wih_bf  = (unsigned short*)(ws + OFF_WIH);
  unsigned short* Whh_bf  = (unsigned short*)(ws + OFF_WHH);
  unsigned short* Wfc_bf  = (unsigned short*)(ws + OFF_WFC);
  float* context          = (float*)(ws + OFF_CTX);
  unsigned short* slow_bf = (unsigned short*)(ws + OFF_SLOW);
  float* gi               = (float*)(ws + OFF_GI);
  unsigned short* Hall    = (unsigned short*)(ws + OFF_HALL);
  unsigned long long* Hall8 = (unsigned long long*)(ws + OFF_HALL);
  unsigned int* flags     = (unsigned int*)(ws + OFF_SYNC);

  hipMemsetAsync(flags, 0, 4096, stream);

  cvt4_kernel<<<4096, 256, 0, stream>>>(W_enc, Wenc_bf, 512 * 8192 / 4);
  cvt4_kernel<<<2048, 256, 0, stream>>>(z_ctx, zctx_bf, 256 * 8192 / 4);
  cvt4_kernel<<<960, 256, 0, stream>>>(W_ih, Wih_bf, 1536 * 640 / 4);
  cvt4_kernel<<<768, 256, 0, stream>>>(W_hh, Whh_bf, 1536 * 512 / 4);
  cvt4_kernel<<<64, 256, 0, stream>>>(W_fc, Wfc_bf, 128 * 512 / 4);

  gemm_bt<1><<<dim3(4, 8), 256, 0, stream>>>(zctx_bf, Wenc_bf, b_enc, context, 256, 512, 8192);
  build_slow_kernel<<<640, 256, 0, stream>>>(context, e, slow_bf);
  gemm_bt<0><<<dim3(4, 24), 256, 0, stream>>>(slow_bf, Wih_bf, b_ih, gi, 256, 1536, 640);

  // distributed GRU scan — 256 WGs at 96 KB LDS = 1 WG/CU, co-resident by
  // construction; cooperative launch preferred, regular launch equivalent.
  {
    const float* gi_c = gi;
    const unsigned short* whh_c = Whh_bf;
    const float* bhh_c = b_hh;
    unsigned long long* hall_c = Hall8;
    unsigned int* flags_c = flags;
    void* args[] = {(void*)&gi_c, (void*)&whh_c, (void*)&bhh_c, (void*)&hall_c, (void*)&flags_c};
    hipError_t err = hipLaunchCooperativeKernel((void*)gru_scan6, dim3(256), dim3(64), args, 0, stream);
    if (err != hipSuccess) {
      gru_scan6<<<256, 64, 0, stream>>>(gi, Whh_bf, b_hh, Hall8, flags);
    }
  }

  fc_scan<<<256, 256, 0, stream>>>(Hall, Wfc_bf, b_fc, z_ctx, out);
}